// Round 9
// baseline (175.851 us; speedup 1.0000x reference)
//
#include <hip/hip_runtime.h>
#include <hip/hip_bf16.h>

typedef __bf16 bf8 __attribute__((ext_vector_type(8)));
typedef float f32x4 __attribute__((ext_vector_type(4)));

#define NBINS 129
#define ROWB 516                 // bytes per input row (129 f32)
#define ITERS 8                  // 16-row tiles per block (128 rows/block)
#define KSTR 136                 // LDS M^T k-stride (elems)
#define MATOFF (64 * KSTR)

__device__ __forceinline__ unsigned short f2bf(float x) {
    return __builtin_bit_cast(unsigned short, (__bf16)x);
}

__global__ __launch_bounds__(256, 4)
void irfft_mm(const float* __restrict__ re,
              const float* __restrict__ im,
              const float* __restrict__ mr,
              const float* __restrict__ mi,
              float* __restrict__ out)
{
    __shared__ unsigned short mt[2 * MATOFF];   // prologue-only M^T staging

    const int tid  = threadIdx.x;
    const int lane = tid & 63;
    const int w    = tid >> 6;   // wave id = output col-block (16 cols)
    const int r16  = lane & 15;
    const int q    = lane >> 4;

    // ---- prologue: M^T -> LDS (bf16), k in [0,128) only; coalesced global reads ----
    for (int e = tid; e < 128 * 64; e += 256) {
        const int k = e >> 6, c = e & 63;
        mt[c * KSTR + k]          = f2bf(mr[e]);
        mt[MATOFF + c * KSTR + k] = f2bf(mi[e]);
    }
    __syncthreads();

    // A-frags: M^T[o = w*16+r16][k = t*32+q*8 .. +8] (held in regs for whole kernel)
    bf8 afr[2][4];
    #pragma unroll
    for (int m = 0; m < 2; ++m)
        #pragma unroll
        for (int t = 0; t < 4; ++t)
            afr[m][t] = *(const bf8*)&mt[m * MATOFF + (w * 16 + r16) * KSTR
                                         + t * 32 + q * 8];
    // k=128 tail coefficients in exact f32
    const f32x4 mtr = *(const f32x4*)(mr + 128 * 64 + w * 16 + q * 4);
    const f32x4 mti = *(const f32x4*)(mi + 128 * 64 + w * 16 + q * 4);

    const long blockrow = (long)blockIdx.x * (ITERS * 16);
    const char* prer = (const char*)re + (blockrow + r16) * (long)ROWB;
    const char* prei = (const char*)im + (blockrow + r16) * (long)ROWB;
    float* pout = out + (blockrow + r16) * 64 + w * 16 + q * 4;

    // single-bank in-flight payload: [mat][t2][pair], 32 VGPRs
    f32x4 vf[2][2][2];
    float trr[2], tri[2];

    // ---- issue phase 0 (it=0, h=0) + tail(0) ----
    #pragma unroll
    for (int m = 0; m < 2; ++m) {
        const char* sp = m ? prei : prer;
        #pragma unroll
        for (int t2 = 0; t2 < 2; ++t2)
            #pragma unroll
            for (int p2 = 0; p2 < 2; ++p2)
                __builtin_memcpy(&vf[m][t2][p2], sp + t2 * 128 + q * 32 + p2 * 16, 16);
    }
    trr[0] = *(const float*)(prer + 512);
    tri[0] = *(const float*)(prei + 512);

    f32x4 acc = {0.f, 0.f, 0.f, 0.f};

    // ---- barrier-free main loop: 16 half-K phases, fully unrolled ----
    #pragma unroll
    for (int p = 0; p < 2 * ITERS; ++p) {
        const int it = p >> 1, h = p & 1;

        // convert current payload (hardware waits on its loads here)
        bf8 bfr[2][2];
        #pragma unroll
        for (int m = 0; m < 2; ++m)
            #pragma unroll
            for (int t2 = 0; t2 < 2; ++t2)
                #pragma unroll
                for (int j = 0; j < 4; ++j) {
                    bfr[m][t2][j]     = (__bf16)vf[m][t2][0][j];
                    bfr[m][t2][4 + j] = (__bf16)vf[m][t2][1][j];
                }

        // issue next phase's loads into the freed payload bank
        if (p + 1 < 2 * ITERS) {
            const int itn = (p + 1) >> 1, hn = (p + 1) & 1;
            const long ro = (long)itn * (16 * ROWB) + hn * 256;
            #pragma unroll
            for (int m = 0; m < 2; ++m) {
                const char* sp = m ? prei : prer;
                #pragma unroll
                for (int t2 = 0; t2 < 2; ++t2)
                    #pragma unroll
                    for (int p2 = 0; p2 < 2; ++p2)
                        __builtin_memcpy(&vf[m][t2][p2],
                                         sp + ro + t2 * 128 + q * 32 + p2 * 16, 16);
            }
            if (hn == 0) {
                trr[itn & 1] = *(const float*)(prer + (long)itn * (16 * ROWB) + 512);
                tri[itn & 1] = *(const float*)(prei + (long)itn * (16 * ROWB) + 512);
            }
        }

        // 4 MFMA for this half-K
        #pragma unroll
        for (int m = 0; m < 2; ++m)
            #pragma unroll
            for (int t2 = 0; t2 < 2; ++t2)
                acc = __builtin_amdgcn_mfma_f32_16x16x32_bf16(
                    afr[m][h * 2 + t2], bfr[m][t2], acc, 0, 0, 0);

        // end of row-tile: f32 rank-1 tail + coalesced store
        if (h) {
            const float xr = trr[it & 1], xi = tri[it & 1];
            #pragma unroll
            for (int jj = 0; jj < 4; ++jj)
                acc[jj] += xr * mtr[jj] + xi * mti[jj];
            *(f32x4*)(pout + (long)it * 1024) = acc;
            acc = (f32x4){0.f, 0.f, 0.f, 0.f};
        }
    }
}

extern "C" void kernel_launch(void* const* d_in, const int* in_sizes, int n_in,
                              void* d_out, int out_size, void* d_ws, size_t ws_size,
                              hipStream_t stream)
{
    const float* re = (const float*)d_in[0];
    const float* im = (const float*)d_in[1];
    const float* mr = (const float*)d_in[2];
    const float* mi = (const float*)d_in[3];
    float* out = (float*)d_out;

    const long rows = (long)in_sizes[0] / NBINS;      // 256000
    const int grid = (int)(rows / (ITERS * 16));      // 2000 (exact)
    irfft_mm<<<grid, 256, 0, stream>>>(re, im, mr, mi, out);
}

// Round 10
// 71.863 us; speedup vs baseline: 2.4470x; 2.4470x over previous
//
#include <hip/hip_runtime.h>
#include <hip/hip_bf16.h>

typedef __bf16 bf8 __attribute__((ext_vector_type(8)));
typedef float f32x4 __attribute__((ext_vector_type(4)));

#define NBINS 129
#define ROWS_IT 16               // rows per iteration
#define ITERS 16                 // iterations per block (256 rows)
#define MATB 8192                // bytes per mat per buffer (16 rows * 512B)
#define BUFB (2 * MATB)          // 16 KB per buffer

__device__ __forceinline__ void gload_lds16(const float* src, char* ldsdst) {
    __builtin_amdgcn_global_load_lds(
        (const __attribute__((address_space(1))) void*)src,
        (__attribute__((address_space(3))) void*)ldsdst, 16, 0, 0);
}

__global__ __launch_bounds__(256, 4)
void irfft_mm(const float* __restrict__ re,
              const float* __restrict__ im,
              const float* __restrict__ mr,
              const float* __restrict__ mi,
              float* __restrict__ out)
{
    __shared__ __align__(16) char lds[2][BUFB];   // 32 KB -> 4 blocks/CU

    const int tid  = threadIdx.x;
    const int lane = tid & 63;
    const int w    = tid >> 6;   // wave id = output col-block (16 cols)
    const int r16  = lane & 15;
    const int q    = lane >> 4;
    const int rk   = r16 & 7;

    const int blockrow = blockIdx.x * (ROWS_IT * ITERS);

    // staging geometry: wave w stages mat (w>>1), tile rows (w&1)*8 .. +7
    const int    smat  = w >> 1;
    const int    srow0 = (w & 1) * 8;
    const float* ssrc  = smat ? im : re;
    const int    lrow  = lane >> 5;   // 0/1: which of the 2 rows per instr
    const int    p     = lane & 31;   // linear 16B-chunk within row

    float trr[2], tri[2];             // k=128 tails (f32), double-buffered

    // ---- prologue: stage batch 0 + its tails ----
    {
        char* b0 = lds[0];
        #pragma unroll
        for (int i = 0; i < 4; ++i) {
            const int trow = srow0 + 2 * i + lrow;
            const int g    = p ^ (trow & 7);          // pre-swizzled global chunk
            gload_lds16(ssrc + (long)(blockrow + trow) * NBINS + g * 4,
                        b0 + smat * MATB + (srow0 + 2 * i) * 512 + lane * 16);
        }
        trr[0] = re[(long)(blockrow + r16) * NBINS + 128];
        tri[0] = im[(long)(blockrow + r16) * NBINS + 128];
    }

    // ---- A fragments (M^T cols w*16..+15) + f32 tail coefficients ----
    bf8 afr[2][4];
    #pragma unroll
    for (int m = 0; m < 2; ++m) {
        const float* M = m ? mi : mr;
        #pragma unroll
        for (int t = 0; t < 4; ++t) {
            bf8 a;
            #pragma unroll
            for (int j = 0; j < 8; ++j)
                a[j] = (__bf16)M[(t * 32 + q * 8 + j) * 64 + w * 16 + r16];
            afr[m][t] = a;
        }
    }
    const f32x4 mt0 = *(const f32x4*)(mr + 128 * 64 + w * 16 + q * 4);
    const f32x4 mt1 = *(const f32x4*)(mi + 128 * 64 + w * 16 + q * 4);

    #pragma unroll
    for (int it = 0; it < ITERS; ++it) {
        char* bufc = lds[it & 1];
        const int rowbase = blockrow + it * ROWS_IT;

        // ---- 1: my batch(it) fully landed (issued one iteration ago) ----
        __builtin_amdgcn_sched_barrier(0);
        asm volatile("s_waitcnt vmcnt(0)" ::: "memory");
        // ---- 2: everyone's batch(it) landed; everyone done compute(it-1) ----
        __builtin_amdgcn_s_barrier();
        __builtin_amdgcn_sched_barrier(0);

        // ---- 3: issue batch(it+1) into the other buffer (flies across compute) ----
        if (it + 1 < ITERS) {
            char* bn = lds[(it + 1) & 1];
            const int rbn = rowbase + ROWS_IT;
            #pragma unroll
            for (int i = 0; i < 4; ++i) {
                const int trow = srow0 + 2 * i + lrow;
                const int g    = p ^ (trow & 7);
                gload_lds16(ssrc + (long)(rbn + trow) * NBINS + g * 4,
                            bn + smat * MATB + (srow0 + 2 * i) * 512 + lane * 16);
            }
            trr[(it + 1) & 1] = re[(long)(rbn + r16) * NBINS + 128];
            tri[(it + 1) & 1] = im[(long)(rbn + r16) * NBINS + 128];
        }

        // ---- 4: compute 16 rows x 16 cols per wave ----
        f32x4 acc = {0.0f, 0.0f, 0.0f, 0.0f};
        #pragma unroll
        for (int m = 0; m < 2; ++m) {
            const char* mb = bufc + m * MATB + r16 * 512;
            #pragma unroll
            for (int t = 0; t < 4; ++t) {
                const int j0 = t * 8 + q * 2;
                const f32x4 lo = *(const f32x4*)(mb + ((j0)     ^ rk) * 16);
                const f32x4 hi = *(const f32x4*)(mb + ((j0 + 1) ^ rk) * 16);
                bf8 bfr;
                #pragma unroll
                for (int jj = 0; jj < 4; ++jj) {
                    bfr[jj]     = (__bf16)lo[jj];
                    bfr[4 + jj] = (__bf16)hi[jj];
                }
                acc = __builtin_amdgcn_mfma_f32_16x16x32_bf16(afr[m][t], bfr, acc, 0, 0, 0);
            }
            // k = 128 rank-1 tail in exact f32
            const float xt = m ? tri[it & 1] : trr[it & 1];
            const f32x4 mt = m ? mt1 : mt0;
            #pragma unroll
            for (int jj = 0; jj < 4; ++jj) acc[jj] += xt * mt[jj];
        }

        // ---- 5: coalesced f32x4 store (waves near-lockstep -> L2 line merge) ----
        *(f32x4*)(out + (long)(rowbase + r16) * 64 + w * 16 + q * 4) = acc;
    }
}

extern "C" void kernel_launch(void* const* d_in, const int* in_sizes, int n_in,
                              void* d_out, int out_size, void* d_ws, size_t ws_size,
                              hipStream_t stream)
{
    const float* re = (const float*)d_in[0];
    const float* im = (const float*)d_in[1];
    const float* mr = (const float*)d_in[2];
    const float* mi = (const float*)d_in[3];
    float* out = (float*)d_out;

    const long rows = (long)in_sizes[0] / NBINS;          // 256000
    const int grid = (int)(rows / (ROWS_IT * ITERS));     // 1000 (exact)
    irfft_mm<<<grid, 256, 0, stream>>>(re, im, mr, mi, out);
}

// Round 11
// 68.023 us; speedup vs baseline: 2.5852x; 1.0565x over previous
//
#include <hip/hip_runtime.h>
#include <hip/hip_bf16.h>

typedef __bf16 bf8 __attribute__((ext_vector_type(8)));
typedef float f32x4 __attribute__((ext_vector_type(4)));

#define NBINS 129
#define ROWS_IT 16               // rows per iteration
#define ITERS 16                 // iterations per block (256 rows)
#define MATB 8192                // bytes per mat per buffer (16 rows * 512B)
#define TAILB 512                // tail area: 2 mats * 16 rows * 16B
#define BUFB (2 * MATB + TAILB)  // 16896 B per buffer

__device__ __forceinline__ void gload_lds16(const float* src, char* ldsdst) {
    __builtin_amdgcn_global_load_lds(
        (const __attribute__((address_space(1))) void*)src,
        (__attribute__((address_space(3))) void*)ldsdst, 16, 0, 0);
}

__global__ __launch_bounds__(256, 3)
void irfft_mm(const float* __restrict__ re,
              const float* __restrict__ im,
              const float* __restrict__ mr,
              const float* __restrict__ mi,
              float* __restrict__ out)
{
    __shared__ __align__(16) char lds[3][BUFB];   // 50688 B -> 3 blocks/CU

    const int tid  = threadIdx.x;
    const int lane = tid & 63;
    const int w    = tid >> 6;   // wave id = output col-block (16 cols)
    const int r16  = lane & 15;
    const int q    = lane >> 4;
    const int rk   = r16 & 7;

    const long blockrow = (long)blockIdx.x * (ROWS_IT * ITERS);

    // staging geometry: wave w stages mat (w>>1), tile rows (w&1)*8 .. +7
    const int    smat  = w >> 1;
    const int    srow0 = (w & 1) * 8;
    const float* ssrc  = smat ? im : re;
    const int    lrow  = lane >> 5;   // 0/1: which of the 2 rows per instr
    const int    p     = lane & 31;   // linear 16B-chunk within row

    // ---- one batch = 5 VMEM ops per wave (4 row-stages + 1 masked tail-stage) ----
    #define STAGE(bn, rbn)                                                        \
        {                                                                         \
            char* _b = (bn);                                                      \
            const long _r = (rbn);                                                \
            _Pragma("unroll")                                                     \
            for (int i = 0; i < 4; ++i) {                                         \
                const int trow = srow0 + 2 * i + lrow;                            \
                const int g    = p ^ (trow & 7);   /* pre-swizzled global chunk */\
                gload_lds16(ssrc + (_r + trow) * (long)NBINS + g * 4,             \
                            _b + smat * MATB + (srow0 + 2 * i) * 512 + lane * 16);\
            }                                                                     \
            if (lane < 8)  /* k=128..131 tail chunk; only k=128 is consumed */    \
                gload_lds16(ssrc + (_r + srow0 + lane) * (long)NBINS + 128,       \
                            _b + 2 * MATB + smat * 256 + (srow0 + lane) * 16);    \
        }

    // ---- prologue: prime pipeline with batches 0 and 1 ----
    STAGE(lds[0], blockrow);
    STAGE(lds[1], blockrow + ROWS_IT);

    // ---- A fragments (M^T cols w*16..+15) + f32 tail coefficients ----
    bf8 afr[2][4];
    #pragma unroll
    for (int m = 0; m < 2; ++m) {
        const float* M = m ? mi : mr;
        #pragma unroll
        for (int t = 0; t < 4; ++t) {
            bf8 a;
            #pragma unroll
            for (int j = 0; j < 8; ++j)
                a[j] = (__bf16)M[(t * 32 + q * 8 + j) * 64 + w * 16 + r16];
            afr[m][t] = a;
        }
    }
    const f32x4 mt0 = *(const f32x4*)(mr + 128 * 64 + w * 16 + q * 4);
    const f32x4 mt1 = *(const f32x4*)(mi + 128 * 64 + w * 16 + q * 4);

    #pragma unroll
    for (int it = 0; it < ITERS; ++it) {
        char* bufc = lds[it % 3];
        const long rowbase = blockrow + it * ROWS_IT;

        // ---- counted wait: batch(it) landed; batch(it+1)'s 5 ops stay in flight ----
        __builtin_amdgcn_sched_barrier(0);
        if (it < ITERS - 1) asm volatile("s_waitcnt vmcnt(5)" ::: "memory");
        else                asm volatile("s_waitcnt vmcnt(0)" ::: "memory");
        __builtin_amdgcn_s_barrier();
        __builtin_amdgcn_sched_barrier(0);

        // ---- issue batch(it+2): has TWO full periods to land ----
        if (it + 2 < ITERS)
            STAGE(lds[(it + 2) % 3], rowbase + 2 * ROWS_IT);

        // ---- compute 16 rows x 16 cols per wave ----
        f32x4 acc = {0.0f, 0.0f, 0.0f, 0.0f};
        #pragma unroll
        for (int m = 0; m < 2; ++m) {
            const char* mb = bufc + m * MATB + r16 * 512;
            #pragma unroll
            for (int t = 0; t < 4; ++t) {
                const int j0 = t * 8 + q * 2;
                const f32x4 lo = *(const f32x4*)(mb + ((j0)     ^ rk) * 16);
                const f32x4 hi = *(const f32x4*)(mb + ((j0 + 1) ^ rk) * 16);
                bf8 bfr;
                #pragma unroll
                for (int jj = 0; jj < 4; ++jj) {
                    bfr[jj]     = (__bf16)lo[jj];
                    bfr[4 + jj] = (__bf16)hi[jj];
                }
                acc = __builtin_amdgcn_mfma_f32_16x16x32_bf16(afr[m][t], bfr, acc, 0, 0, 0);
            }
            // k = 128 rank-1 tail in exact f32 (from the DMA-staged tail area)
            const float xt = *(const float*)(bufc + 2 * MATB + m * 256 + r16 * 16);
            const f32x4 mt = m ? mt1 : mt0;
            #pragma unroll
            for (int jj = 0; jj < 4; ++jj) acc[jj] += xt * mt[jj];
        }

        // ---- coalesced f32x4 store ----
        *(f32x4*)(out + (rowbase + r16) * 64 + w * 16 + q * 4) = acc;
    }
    #undef STAGE
}

extern "C" void kernel_launch(void* const* d_in, const int* in_sizes, int n_in,
                              void* d_out, int out_size, void* d_ws, size_t ws_size,
                              hipStream_t stream)
{
    const float* re = (const float*)d_in[0];
    const float* im = (const float*)d_in[1];
    const float* mr = (const float*)d_in[2];
    const float* mi = (const float*)d_in[3];
    float* out = (float*)d_out;

    const long rows = (long)in_sizes[0] / NBINS;          // 256000
    const int grid = (int)(rows / (ROWS_IT * ITERS));     // 1000 (exact)
    irfft_mm<<<grid, 256, 0, stream>>>(re, im, mr, mi, out);
}